// Round 2
// baseline (954.055 us; speedup 1.0000x reference)
//
#include <hip/hip_runtime.h>

// PowerSpectrum: out[s,n, l*f^2 + i*f + j] = (2l+1)^{-1/2} * sum_m c_l[s,n,m,i]*c_l[s,n,m,j]
// f = 128, m-count = 2l+1 (1,3,5,7), S*N = 2000.
// Write-bound: 524 MB output vs 16 MB input -> target plain-store HBM ceiling (~6.4 TB/s,
// proven by the harness fill kernel).
//
// R1 lesson: 4 serial dispatches x 2000 coarse blocks ran at 1.1 TB/s. This round:
// ONE dispatch, 16 blocks per (s,n) gram matrix (4 l's x 4 row-chunks), 32000 blocks
// of 256 threads, 4 float4 stores per thread, fully coalesced.

#define NFEAT 128

__device__ __constant__ float kCg[4] = {
    1.0f,
    0.57735026918962576451f,   // 1/sqrt(3)
    0.44721359549995793928f,   // 1/sqrt(5)
    0.37796447300922722721f};  // 1/sqrt(7)

__global__ __launch_bounds__(256) void ps_fused(const float* __restrict__ c0,
                                                const float* __restrict__ c1,
                                                const float* __restrict__ c2,
                                                const float* __restrict__ c3,
                                                float* __restrict__ out) {
  __shared__ float sc[7 * NFEAT];  // max nm=7 rows of 128 floats (3.5 KB)

  const int bid   = blockIdx.x;
  const int sn    = bid >> 4;       // (s,n) index
  const int r     = bid & 15;
  const int l     = r >> 2;         // 0..3
  const int chunk = r & 3;          // which 32-row slice of the 128x128 output
  const int nm    = 2 * l + 1;
  const int tid   = threadIdx.x;

  const float* c = (l == 0) ? c0 : (l == 1) ? c1 : (l == 2) ? c2 : c3;

  // Stage this (s,n,l) c-tile: nm*128 floats = nm*32 float4 (<=224 <= 256 threads)
  const float* src = c + (size_t)sn * ((size_t)nm * NFEAT);
  if (tid < nm * 32) {
    ((float4*)sc)[tid] = ((const float4*)src)[tid];
  }
  __syncthreads();

  const int j4 = tid & 31;   // float4 column 0..31
  const int i0 = tid >> 5;   // row phase 0..7

  // B fragment: c[m][4*j4..4*j4+3] in registers (max 7 float4 = 28 VGPR)
  float4 b[7];
  for (int m = 0; m < nm; ++m) b[m] = ((const float4*)sc)[m * 32 + j4];

  const float cg = kCg[l];
  float* obase = out + (size_t)sn * (4 * NFEAT * NFEAT)
                     + (size_t)l * (NFEAT * NFEAT)
                     + (size_t)chunk * 32 * NFEAT;

  for (int k = 0; k < 4; ++k) {
    const int i = i0 + 8 * k;               // row within this 32-row chunk
    const int row = chunk * 32 + i;         // row within the full 128
    float4 acc = {0.f, 0.f, 0.f, 0.f};
    for (int m = 0; m < nm; ++m) {
      const float a = sc[m * NFEAT + row];  // wave-broadcast LDS read
      acc.x += a * b[m].x;
      acc.y += a * b[m].y;
      acc.z += a * b[m].z;
      acc.w += a * b[m].w;
    }
    acc.x *= cg; acc.y *= cg; acc.z *= cg; acc.w *= cg;
    ((float4*)(obase + i * NFEAT))[j4] = acc;  // wave writes 1 KB contiguous
  }
}

extern "C" void kernel_launch(void* const* d_in, const int* in_sizes, int n_in,
                              void* d_out, int out_size, void* d_ws, size_t ws_size,
                              hipStream_t stream) {
  const float* c0 = (const float*)d_in[0];
  const float* c1 = (const float*)d_in[1];
  const float* c2 = (const float*)d_in[2];
  const float* c3 = (const float*)d_in[3];
  float* out = (float*)d_out;

  const int nsn = in_sizes[0] / NFEAT;  // S*N from l=0 input (S,N,1,128)

  dim3 block(256);
  dim3 grid(nsn * 16);  // 4 l's x 4 row-chunks per (s,n)
  ps_fused<<<grid, block, 0, stream>>>(c0, c1, c2, c3, out);
}